// Round 8
// baseline (136.943 us; speedup 1.0000x reference)
//
#include <hip/hip_runtime.h>
#include <math.h>

// Problem constants
#define BATCH 64
#define SEQL  512
#define DIN   256
#define NF    256
#define KS    3
#define KF    (KS * NF)        // 768

// Fully fused combined-channel formulation, 2-blocks/CU edition:
//   One block = (b, 64-row slab). Panels P0/P1 = bf16 x (ch 0..127 / 128..255),
//   rows l0-1..l0+64 (66 rows). Phase G computes Y = (x@U)*sigmoid(z) into
//   registers (accY[4][5], operand-swapped MFMA so lanes hold consecutive e);
//   then conv g=0 consumes P0, Y[e0..127] overwrites P0; conv g=1 consumes
//   P1, Y[e128..255] overwrites P1; conv g=2,3 consume the Y panels.
//   All staging via 2x16KB dbuf, issue-early. LDS 65 KB -> 2 blocks/CU.
#define XCH 512
#define KC  (KS * XCH)          // 1536
#define PR2 66                  // 64 out rows + 2 halo
#define PLD 128                 // panel row stride in shorts (256 B)
#define P0SZ (PR2 * PLD)        // 8448 shorts

typedef __attribute__((ext_vector_type(8))) short short8;
typedef __attribute__((ext_vector_type(4))) float floatx4;
typedef __attribute__((ext_vector_type(16))) float floatx16;
typedef __attribute__((ext_vector_type(8))) unsigned short ushort8v;
typedef __attribute__((ext_vector_type(4))) unsigned short ushort4v;

static __device__ __forceinline__ unsigned short f2bf(float f) {
    unsigned int u = __float_as_uint(f);
    return (unsigned short)((u + 0x7FFF + ((u >> 16) & 1)) >> 16);  // RTNE
}

// async 16B/lane global->LDS; LDS dst = wave-uniform base + lane*16
static __device__ __forceinline__ void gl_lds16(const void* g, void* l) {
    __builtin_amdgcn_global_load_lds(
        (const __attribute__((address_space(1))) unsigned int*)g,
        (__attribute__((address_space(3))) unsigned int*)l, 16, 0, 0);
}

// ---------------------------------------------------------------------------
// pack: WcT[f][c] transpose (96 blk), UT[e][d] transpose (16 blk).
// 112 blocks x 256 threads.
// ---------------------------------------------------------------------------
__global__ __launch_bounds__(256) void pack_kernel(
    const float* __restrict__ U, const float* __restrict__ V,
    const float* __restrict__ Bw,
    unsigned short* __restrict__ WcT, unsigned short* __restrict__ UT)
{
    const int blk = blockIdx.x;
    const int t   = threadIdx.x;
    __shared__ unsigned short tile[64][64 + 2];

    if (blk < 96) {
        const int f0 = (blk & 3) * 64, c0 = (blk >> 2) * 64;
        const int fl = t & 63, cb = t >> 6;
        #pragma unroll
        for (int it = 0; it < 16; ++it) {
            const int cl = cb + it * 4;
            const int c  = c0 + cl;
            const int k  = c >> 9, ch = c & (XCH - 1);
            const float v = (ch < DIN) ? Bw[(size_t)ch * KF + k * NF + f0 + fl]
                                       : V[(size_t)(ch - DIN) * KF + k * NF + f0 + fl];
            tile[cl][fl] = f2bf(v);
        }
        __syncthreads();
        const int cl2 = t & 63, fb = t >> 6;
        #pragma unroll
        for (int it = 0; it < 16; ++it) {
            const int fl2 = fb + it * 4;
            WcT[(size_t)(f0 + fl2) * KC + c0 + cl2] = tile[cl2][fl2];
        }
    } else {
        const int bb = blk - 96;
        const int e0 = (bb & 3) * 64, d0 = (bb >> 2) * 64;
        const int el = t & 63, db = t >> 6;
        #pragma unroll
        for (int it = 0; it < 16; ++it) {
            const int dl = db + it * 4;
            tile[dl][el] = f2bf(U[(size_t)(d0 + dl) * DIN + e0 + el]);
        }
        __syncthreads();
        const int dl2 = t & 63, eb = t >> 6;
        #pragma unroll
        for (int it = 0; it < 16; ++it) {
            const int el2 = eb + it * 4;
            UT[(size_t)(e0 + el2) * DIN + d0 + dl2] = tile[dl2][el2];
        }
    }
}

// ---------------------------------------------------------------------------
// fused kernel. Grid 512 x 256. LDS 66560 B -> 2 blocks/CU (8 waves/CU).
// ---------------------------------------------------------------------------
__global__ __launch_bounds__(256, 2) void fused_kernel(
    const float* __restrict__ x, const float* __restrict__ z,
    const unsigned short* __restrict__ UT,
    const unsigned short* __restrict__ WcT,
    const float* __restrict__ bias, float* __restrict__ out)
{
    __shared__ __align__(16) unsigned short lds[2 * P0SZ + 2 * 8192]; // 66560 B
    unsigned short* P0 = lds;
    unsigned short* P1 = lds + P0SZ;
    unsigned short* Bs = lds + 2 * P0SZ;     // 2 x 8192 shorts (16 KB each)

    const int tid  = threadIdx.x;
    const int lane = tid & 63;
    const int wave = tid >> 6;               // 0..3
    const int quad = lane >> 4, l16 = lane & 15;
    const int l32  = lane & 31, hi  = lane >> 5;
    const int r4   = lane >> 2, ud4 = lane & 3;

    const int bid = blockIdx.x;
    const int b   = bid >> 3;
    const int l0  = (bid & 7) * 64;

    floatx16 acc2[2][2] = {};                // conv acc: 64x64 per wave
    floatx4  accY[4][5] = {};                // G acc: 4 e-tiles x 5 row-tiles

    // stage a [256 rows][32 shorts] tile (row stride rs) into 16KB buf.
    // 16B units XOR-swizzled: slot = src_unit ^ (row&3). 4 calls/wave.
    auto stage32 = [&](const unsigned short* gbase, size_t rs,
                       unsigned short* buf) {
        #pragma unroll
        for (int c = 0; c < 4; ++c) {
            const int rr = wave * 64 + c * 16 + r4;
            gl_lds16(gbase + (size_t)rr * rs + ((ud4 ^ (rr & 3)) << 3),
                     buf + (size_t)(wave * 64 + c * 16) * 32);
        }
    };
    // conv region r = (g*3+k)*4 + hq : WcT[256 f][32 ch]
    auto stageB = [&](int r) {
        const int g = r / 12, k = (r / 4) % 3, hq = r & 3;
        stage32(WcT + (size_t)k * XCH + g * 128 + hq * 32, KC,
                Bs + (size_t)(r & 1) * 8192);
    };
    auto stageU = [&](int kk) {              // UT[256 e][32 d], chunk kk
        stage32(UT + (size_t)kk * 32, DIN, Bs + (size_t)(kk & 1) * 8192);
    };

    // conv compute region r: 2 ks x (af[2]+bf[2] -> 4 MFMA 32x32x16)
    auto convRegion = [&](int r) {
        const unsigned short* buf = Bs + (size_t)(r & 1) * 8192;
        const int g = r / 12, k = (r / 4) % 3, hq = r & 3;
        const unsigned short* P = (g & 1) ? P1 : P0;
        __builtin_amdgcn_s_setprio(1);
        #pragma unroll
        for (int ks = 0; ks < 2; ++ks) {
            short8 af[2], bf[2];
            const int ua = hq * 4 + ks * 2 + hi;
            #pragma unroll
            for (int i = 0; i < 2; ++i) {
                const int m = i * 32 + l32 + k;              // 0..65
                af[i] = *(const short8*)&P[m * PLD + ((ua ^ (m & 15)) << 3)];
            }
            const int ub = ks * 2 + hi;
            #pragma unroll
            for (int j = 0; j < 2; ++j) {
                const int n = wave * 64 + j * 32 + l32;      // f row
                bf[j] = *(const short8*)&buf[n * 32 + ((ub ^ (n & 3)) << 3)];
            }
            #pragma unroll
            for (int i = 0; i < 2; ++i)
                #pragma unroll
                for (int j = 0; j < 2; ++j)
                    acc2[i][j] = __builtin_amdgcn_mfma_f32_32x32x16_bf16(
                        af[i], bf[j], acc2[i][j], 0, 0, 0);
        }
        __builtin_amdgcn_s_setprio(0);
    };

    // G compute chunk kk (32 d): uf[4] + xf[5] -> 20 MFMA 16x16x32.
    // Operand-swapped: D[e][xrow].
    auto gChunk = [&](int kk) {
        const unsigned short* buf = Bs + (size_t)(kk & 1) * 8192;
        const unsigned short* P = (kk >= 4) ? P1 : P0;
        const int ux = (kk & 3) * 4 + quad;
        __builtin_amdgcn_s_setprio(1);
        short8 uf[4];
        #pragma unroll
        for (int q = 0; q < 4; ++q) {
            const int n = q * 64 + wave * 16 + l16;          // e row
            uf[q] = *(const short8*)&buf[n * 32 + ((quad ^ (n & 3)) << 3)];
        }
        #pragma unroll
        for (int i = 0; i < 5; ++i) {
            const int row = i * 16 + l16;   // x row; >=66 garbage, masked later
            const short8 xf = *(const short8*)
                &P[row * PLD + ((ux ^ (row & 15)) << 3)];
            #pragma unroll
            for (int q = 0; q < 4; ++q)
                accY[q][i] = __builtin_amdgcn_mfma_f32_16x16x32_bf16(
                    uf[q], xf, accY[q][i], 0, 0, 0);
        }
        __builtin_amdgcn_s_setprio(0);
    };

    // Y epilogue half eh: q = eh*2 + {0,1}; lane holds 4 consecutive e.
    auto yEpi = [&](int eh) {
        unsigned short* PY = eh ? P1 : P0;
        #pragma unroll
        for (int q2 = 0; q2 < 2; ++q2) {
            const int q  = eh * 2 + q2;
            const int e0 = (q * 4 + wave) * 16 + quad * 4;   // 0..252
            const int c0 = e0 & 127;
            float zf[4];
            #pragma unroll
            for (int r2 = 0; r2 < 4; ++r2)
                zf[r2] = 1.0f / (1.0f + expf(-z[(size_t)b * DIN + e0 + r2]));
            const int u = c0 >> 3;
            #pragma unroll
            for (int i = 0; i < 5; ++i) {
                const int xrow = i * 16 + l16;
                if (xrow < PR2) {
                    ushort4v h;
                    #pragma unroll
                    for (int r2 = 0; r2 < 4; ++r2)
                        h[r2] = f2bf(accY[q][i][r2] * zf[r2]);
                    *(ushort4v*)&PY[xrow * PLD + ((u ^ (xrow & 15)) << 3) +
                                    (c0 & 7)] = h;
                }
            }
        }
    };

    // ---------------- phase X: x -> P0, P1 (bf16, swizzled) ----------------
    #pragma unroll
    for (int p = 0; p < 2; ++p) {
        unsigned short* P = p ? P1 : P0;
        #pragma unroll
        for (int it = 0; it < 5; ++it) {
            const int idx = tid + it * 256;
            if (idx < PR2 * 16) {
                const int row = idx >> 4, u = idx & 15;
                const int l = l0 - 1 + row;
                ushort8v h = {};
                if (l >= 0 && l < SEQL) {
                    const float* xp =
                        x + ((size_t)b * SEQL + l) * DIN + p * 128 + u * 8;
                    const float4 v0 = *(const float4*)xp;
                    const float4 v1 = *(const float4*)(xp + 4);
                    h[0] = f2bf(v0.x); h[1] = f2bf(v0.y);
                    h[2] = f2bf(v0.z); h[3] = f2bf(v0.w);
                    h[4] = f2bf(v1.x); h[5] = f2bf(v1.y);
                    h[6] = f2bf(v1.z); h[7] = f2bf(v1.w);
                }
                *(ushort8v*)&P[row * PLD + ((u ^ (row & 15)) << 3)] = h;
            }
        }
    }

    // ---------------- phase G: Y into accY (8 chunks of 32 d) --------------
    stageU(0);
    __syncthreads();                 // X writes visible + stageU(0) landed
    #pragma unroll 1
    for (int kk = 0; kk < 8; ++kk) {
        if (kk < 7) stageU(kk + 1); else stageB(0);   // issue-early
        gChunk(kk);
        __syncthreads();
    }

    // ---------------- conv g=0 (P0=x low) ----------------------------------
    #pragma unroll 1
    for (int r = 0; r < 12; ++r) { stageB(r + 1); convRegion(r); __syncthreads(); }
    yEpi(0);                         // overwrite P0 with Y[e 0..127]

    // ---------------- conv g=1 (P1=x high) ---------------------------------
    #pragma unroll 1
    for (int r = 12; r < 24; ++r) { stageB(r + 1); convRegion(r); __syncthreads(); }
    yEpi(1);                         // overwrite P1 with Y[e 128..255]

    // ---------------- conv g=2,3 (Y panels) --------------------------------
    #pragma unroll 1
    for (int r = 24; r < 48; ++r) {
        if (r < 47) stageB(r + 1);
        convRegion(r);
        __syncthreads();
    }

    // ---------------- epilogue: bias + relu -> out -------------------------
    #pragma unroll
    for (int j = 0; j < 2; ++j) {
        const int f  = wave * 64 + j * 32 + l32;
        const float bv = bias[f];
        #pragma unroll
        for (int i = 0; i < 2; ++i) {
            #pragma unroll
            for (int reg = 0; reg < 16; ++reg) {
                const int rowl = i * 32 + (reg & 3) + 8 * (reg >> 2) + 4 * hi;
                const float v = acc2[i][j][reg] + bv;
                out[((size_t)b * SEQL + l0 + rowl) * NF + f] = fmaxf(v, 0.0f);
            }
        }
    }
}

extern "C" void kernel_launch(void* const* d_in, const int* in_sizes, int n_in,
                              void* d_out, int out_size, void* d_ws, size_t ws_size,
                              hipStream_t stream) {
    const float* x    = (const float*)d_in[0];
    const float* z    = (const float*)d_in[1];
    const float* U    = (const float*)d_in[2];
    const float* V    = (const float*)d_in[3];
    const float* Bw   = (const float*)d_in[4];
    const float* bias = (const float*)d_in[5];

    unsigned short* WcT = (unsigned short*)d_ws;          // 256*1536*2 B
    unsigned short* UT  = WcT + (size_t)NF * KC;          // 256*256*2 B
    float* out = (float*)d_out;

    pack_kernel<<<dim3(112), 256, 0, stream>>>(U, V, Bw, WcT, UT);
    fused_kernel<<<dim3(512), 256, 0, stream>>>(x, z, UT, WcT, bias, out);
}

// Round 9
// 131.272 us; speedup vs baseline: 1.0432x; 1.0432x over previous
//
#include <hip/hip_runtime.h>
#include <math.h>

// Problem constants
#define BATCH 64
#define SEQL  512
#define DIN   256
#define NF    256
#define KS    3
#define KF    (KS * NF)        // 768

// Fully fused combined-channel formulation (round-5 structure) with a
// counted-vmcnt ring pipeline (T3+T4):
//   panels P0..P3 = [130][128] bf16 (x lo/hi, Y lo/hi), 133 KB total.
//   staging = ring of 4 x 16KB slots, 2-deep prefetch, ONE raw s_barrier +
//   s_waitcnt vmcnt(4) per region (tail: 2 -> 0). Never vmcnt(0) in steady
//   state -- the round-5 __syncthreads() drain was the measured stall.
//   Staged tiles are [256 rows][32 shorts] pair-packed as [128 lds-rows]
//   [64 shorts] (128-B rows) to keep bf-read bank conflicts at round-5 level.
#define XCH 512
#define KC  (KS * XCH)          // 1536
#define PROWS 130               // 128 out rows + 2 halo
#define PLD   128               // panel row stride (shorts) = 256 B
#define PSZ   (PROWS * PLD)     // 16640 shorts per panel
#define SLOT  8192              // ring slot, shorts (16 KB)

typedef __attribute__((ext_vector_type(8))) short short8;
typedef __attribute__((ext_vector_type(4))) float floatx4;
typedef __attribute__((ext_vector_type(16))) float floatx16;
typedef __attribute__((ext_vector_type(8))) unsigned short ushort8v;
typedef __attribute__((ext_vector_type(4))) unsigned short ushort4v;

static __device__ __forceinline__ unsigned short f2bf(float f) {
    unsigned int u = __float_as_uint(f);
    return (unsigned short)((u + 0x7FFF + ((u >> 16) & 1)) >> 16);  // RTNE
}

// async 16B/lane global->LDS; LDS dst = wave-uniform base + lane*16
static __device__ __forceinline__ void gl_lds16(const void* g, void* l) {
    __builtin_amdgcn_global_load_lds(
        (const __attribute__((address_space(1))) unsigned int*)g,
        (__attribute__((address_space(3))) unsigned int*)l, 16, 0, 0);
}

// counted-vmcnt barrier: wait for the region's staging (2 loads/stage/wave),
// keep up to 2 stages in flight. "memory" clobber + sched_barrier(0) per
// guide rule #18 (prevent ds_read/MFMA hoisting above the wait).
#define PIPE_WAIT(rem)                                                       \
    do {                                                                     \
        if ((rem) >= 2)                                                      \
            asm volatile("s_waitcnt vmcnt(4) lgkmcnt(0)" ::: "memory");      \
        else if ((rem) == 1)                                                 \
            asm volatile("s_waitcnt vmcnt(2) lgkmcnt(0)" ::: "memory");      \
        else                                                                 \
            asm volatile("s_waitcnt vmcnt(0) lgkmcnt(0)" ::: "memory");      \
        __builtin_amdgcn_s_barrier();                                        \
        __builtin_amdgcn_sched_barrier(0);                                   \
    } while (0)

// ---------------------------------------------------------------------------
// pack: WcT[f][c] transpose (96 blk), UT[e][d] transpose (16 blk).
// 112 blocks x 256 threads.
// ---------------------------------------------------------------------------
__global__ __launch_bounds__(256) void pack_kernel(
    const float* __restrict__ U, const float* __restrict__ V,
    const float* __restrict__ Bw,
    unsigned short* __restrict__ WcT, unsigned short* __restrict__ UT)
{
    const int blk = blockIdx.x;
    const int t   = threadIdx.x;
    __shared__ unsigned short tile[64][64 + 2];

    if (blk < 96) {
        const int f0 = (blk & 3) * 64, c0 = (blk >> 2) * 64;
        const int fl = t & 63, cb = t >> 6;
        #pragma unroll
        for (int it = 0; it < 16; ++it) {
            const int cl = cb + it * 4;
            const int c  = c0 + cl;
            const int k  = c >> 9, ch = c & (XCH - 1);
            const float v = (ch < DIN) ? Bw[(size_t)ch * KF + k * NF + f0 + fl]
                                       : V[(size_t)(ch - DIN) * KF + k * NF + f0 + fl];
            tile[cl][fl] = f2bf(v);
        }
        __syncthreads();
        const int cl2 = t & 63, fb = t >> 6;
        #pragma unroll
        for (int it = 0; it < 16; ++it) {
            const int fl2 = fb + it * 4;
            WcT[(size_t)(f0 + fl2) * KC + c0 + cl2] = tile[cl2][fl2];
        }
    } else {
        const int bb = blk - 96;
        const int e0 = (bb & 3) * 64, d0 = (bb >> 2) * 64;
        const int el = t & 63, db = t >> 6;
        #pragma unroll
        for (int it = 0; it < 16; ++it) {
            const int dl = db + it * 4;
            tile[dl][el] = f2bf(U[(size_t)(d0 + dl) * DIN + e0 + el]);
        }
        __syncthreads();
        const int dl2 = t & 63, eb = t >> 6;
        #pragma unroll
        for (int it = 0; it < 16; ++it) {
            const int el2 = eb + it * 4;
            UT[(size_t)(e0 + el2) * DIN + d0 + dl2] = tile[dl2][el2];
        }
    }
}

// ---------------------------------------------------------------------------
// fused kernel. Grid 256 x 512. LDS 133.1 KB -> 1 block/CU (8 waves).
// ---------------------------------------------------------------------------
__global__ __launch_bounds__(512, 2) void fused_kernel(
    const float* __restrict__ x, const float* __restrict__ z,
    const unsigned short* __restrict__ UT,
    const unsigned short* __restrict__ WcT,
    const float* __restrict__ bias, float* __restrict__ out)
{
    __shared__ __align__(16) unsigned short lds[4 * PSZ];   // 133120 B

    const int tid  = threadIdx.x;
    const int lane = tid & 63;
    const int wave = tid >> 6;               // 0..7
    const int quad = lane >> 4, l16 = lane & 15;
    const int l32  = lane & 31, hi  = lane >> 5;

    const int bid   = blockIdx.x;
    const int b     = bid >> 2;
    const int lbase = (bid & 3) * 128;

    const int wr = wave >> 2, wcv = wave & 3;  // conv: 2x4 grid of 64x64 tiles

    floatx16 acc2[2][2] = {};                  // conv acc, live whole kernel

    unsigned short* RA = lds + 2 * PSZ;        // conv-A + G ring (P2/P3 space)
    unsigned short* RB = lds;                  // conv-B ring (P0/P1 space)

    // stage a [256 gr][32 shorts] tile (global row stride rs) into a 16KB
    // slot, pair-packed: lds_row = gr>>1 (64 shorts = 128 B), unit
    // u8 = (gr&1)*4 + (chunk ^ (lds_row&3)). 2 gl_lds16 per wave.
    auto stagePair = [&](const unsigned short* gbase, size_t rs,
                         unsigned short* buf) {
        #pragma unroll
        for (int c = 0; c < 2; ++c) {
            const int group = wave * 2 + c;           // 0..15
            const int lr    = group * 8 + (lane >> 3);// lds row 0..127
            const int gr    = lr * 2 + ((lane >> 2) & 1);
            const int chunk = (lane & 3) ^ (lr & 3);
            gl_lds16(gbase + (size_t)gr * rs + chunk * 8,
                     buf + (size_t)group * 512);
        }
    };
    // conv region r = (g*3 + k)*4 + cq : WcT[256 f][32 ch]
    auto stageB = [&](int r) {
        const int g = r / 12, k = (r >> 2) % 3, cq = r & 3;
        stagePair(WcT + (size_t)k * XCH + g * 128 + cq * 32, KC,
                  ((r < 24) ? RA : RB) + (size_t)(r & 3) * SLOT);
    };
    auto stageU = [&](int kk) {                 // UT[256 e][32 d], chunk kk
        stagePair(UT + (size_t)kk * 32, DIN, RA + (size_t)(kk & 3) * SLOT);
    };

    // conv compute region r: 2 ks x (af[2]+bf[2] -> 4 MFMA 32x32x16)
    auto convRegion = [&](int r) {
        const unsigned short* buf =
            ((r < 24) ? RA : RB) + (size_t)(r & 3) * SLOT;
        const int g = r / 12, k = (r >> 2) % 3, cq = r & 3;
        const unsigned short* P = lds + (size_t)g * PSZ;
        __builtin_amdgcn_s_setprio(1);
        #pragma unroll
        for (int ks = 0; ks < 2; ++ks) {
            short8 af[2], bf[2];
            const int ua = cq * 4 + ks * 2 + hi;
            #pragma unroll
            for (int i = 0; i < 2; ++i) {
                const int m = wr * 64 + i * 32 + l32 + k;   // 0..129
                af[i] = *(const short8*)&P[m * PLD + ((ua ^ (m & 15)) << 3)];
            }
            const int ci = ks * 2 + hi;
            #pragma unroll
            for (int j = 0; j < 2; ++j) {
                const int n = wcv * 64 + j * 32 + l32;      // f row 0..255
                bf[j] = *(const short8*)
                    &buf[(n >> 1) * 64 +
                         ((((n & 1) * 4) + (ci ^ ((n >> 1) & 3))) << 3)];
            }
            #pragma unroll
            for (int i = 0; i < 2; ++i)
                #pragma unroll
                for (int j = 0; j < 2; ++j)
                    acc2[i][j] = __builtin_amdgcn_mfma_f32_32x32x16_bf16(
                        af[i], bf[j], acc2[i][j], 0, 0, 0);
        }
        __builtin_amdgcn_s_setprio(0);
    };

    // ---------------- prologue: first conv-A stages, then phase X ----------
    stageB(0); stageB(1); stageB(2);          // 6 loads in flight

    #pragma unroll
    for (int p = 0; p < 2; ++p) {
        unsigned short* P = lds + (size_t)p * PSZ;
        #pragma unroll
        for (int it = 0; it < 5; ++it) {
            const int idx = tid + it * 512;
            if (idx < PROWS * 16) {
                const int row = idx >> 4, u = idx & 15;
                const int l = lbase - 1 + row;
                ushort8v h = {};
                if (l >= 0 && l < SEQL) {
                    const float* xp =
                        x + ((size_t)b * SEQL + l) * DIN + p * 128 + u * 8;
                    const float4 v0 = *(const float4*)xp;
                    const float4 v1 = *(const float4*)(xp + 4);
                    h[0] = f2bf(v0.x); h[1] = f2bf(v0.y);
                    h[2] = f2bf(v0.z); h[3] = f2bf(v0.w);
                    h[4] = f2bf(v1.x); h[5] = f2bf(v1.y);
                    h[6] = f2bf(v1.z); h[7] = f2bf(v1.w);
                }
                *(ushort8v*)&P[row * PLD + ((u ^ (row & 15)) << 3)] = h;
            }
        }
    }

    // ---------------- conv part A: g = 0,1 (x panels), regions 0..23 -------
    #pragma unroll 1
    for (int r = 0; r < 24; ++r) {
        PIPE_WAIT(23 - r);
        if (r + 3 < 24) stageB(r + 3);
        convRegion(r);
    }

    // ---------------- phase G: Y = (x@U)*sigmoid(z), operand-swapped -------
    {
        floatx4 accY[2][9] = {};
        stageU(0); stageU(1); stageU(2);      // slots 0..2 (tiles 20..22 done)
        #pragma unroll 1
        for (int kk = 0; kk < 8; ++kk) {
            PIPE_WAIT(7 - kk);
            if (kk + 3 < 8) stageU(kk + 3);
            const unsigned short* buf = RA + (size_t)(kk & 3) * SLOT;
            const unsigned short* P = lds + (size_t)((kk >= 4) ? 1 : 0) * PSZ;
            const int ub = (kk & 3) * 4 + quad;
            __builtin_amdgcn_s_setprio(1);
            short8 uf[2];
            #pragma unroll
            for (int eh = 0; eh < 2; ++eh) {
                const int n = eh * 128 + wave * 16 + l16;   // e row
                uf[eh] = *(const short8*)
                    &buf[(n >> 1) * 64 +
                         ((((n & 1) * 4) + (quad ^ ((n >> 1) & 3))) << 3)];
            }
            #pragma unroll
            for (int i = 0; i < 9; ++i) {
                const int row = i * 16 + l16;  // x row; >=130 garbage, masked
                const short8 xf = *(const short8*)
                    &P[row * PLD + ((ub ^ (row & 15)) << 3)];
                #pragma unroll
                for (int eh = 0; eh < 2; ++eh)
                    accY[eh][i] = __builtin_amdgcn_mfma_f32_16x16x32_bf16(
                        uf[eh], xf, accY[eh][i], 0, 0, 0);
            }
            __builtin_amdgcn_s_setprio(0);
        }
        // barrier: all waves done reading ring slot 3 before yEpi overwrites
        asm volatile("s_waitcnt lgkmcnt(0)" ::: "memory");
        __builtin_amdgcn_s_barrier();
        __builtin_amdgcn_sched_barrier(0);

        // Y epilogue: lane holds 4 consecutive e (D[e][xrow]); b64 writes.
        #pragma unroll
        for (int eh = 0; eh < 2; ++eh) {
            unsigned short* PY = lds + (size_t)(2 + eh) * PSZ;
            const int c0 = wave * 16 + quad * 4;            // 0..124
            float zf[4];
            #pragma unroll
            for (int r2 = 0; r2 < 4; ++r2)
                zf[r2] = 1.0f /
                    (1.0f + expf(-z[(size_t)b * DIN + eh * 128 + c0 + r2]));
            const int u = c0 >> 3;
            #pragma unroll
            for (int i = 0; i < 9; ++i) {
                const int xrow = i * 16 + l16;
                if (xrow < PROWS) {
                    ushort4v h;
                    #pragma unroll
                    for (int r2 = 0; r2 < 4; ++r2)
                        h[r2] = f2bf(accY[eh][i][r2] * zf[r2]);
                    *(ushort4v*)&PY[xrow * PLD + ((u ^ (xrow & 15)) << 3) +
                                    (c0 & 7)] = h;
                }
            }
        }
    }

    // ---------------- conv part B: g = 2,3 (Y panels), regions 24..47 ------
    // ring RB in P0/P1 space (x panels dead after G; post-G barrier passed).
    stageB(24); stageB(25); stageB(26);
    #pragma unroll 1
    for (int r = 24; r < 48; ++r) {
        PIPE_WAIT(47 - r);                    // 1st iter lgkm(0) covers yEpi
        if (r + 3 < 48) stageB(r + 3);
        convRegion(r);
    }

    // ---------------- epilogue: bias + relu -> out -------------------------
    #pragma unroll
    for (int j = 0; j < 2; ++j) {
        const int f  = wcv * 64 + j * 32 + l32;
        const float bv = bias[f];
        #pragma unroll
        for (int i = 0; i < 2; ++i) {
            #pragma unroll
            for (int reg = 0; reg < 16; ++reg) {
                const int rowl = wr * 64 + i * 32 +
                                 (reg & 3) + 8 * (reg >> 2) + 4 * hi;
                const float v = acc2[i][j][reg] + bv;
                out[((size_t)b * SEQL + lbase + rowl) * NF + f] = fmaxf(v, 0.0f);
            }
        }
    }
}

extern "C" void kernel_launch(void* const* d_in, const int* in_sizes, int n_in,
                              void* d_out, int out_size, void* d_ws, size_t ws_size,
                              hipStream_t stream) {
    const float* x    = (const float*)d_in[0];
    const float* z    = (const float*)d_in[1];
    const float* U    = (const float*)d_in[2];
    const float* V    = (const float*)d_in[3];
    const float* Bw   = (const float*)d_in[4];
    const float* bias = (const float*)d_in[5];

    unsigned short* WcT = (unsigned short*)d_ws;          // 256*1536*2 B
    unsigned short* UT  = WcT + (size_t)NF * KC;          // 256*256*2 B
    float* out = (float*)d_out;

    pack_kernel<<<dim3(112), 256, 0, stream>>>(U, V, Bw, WcT, UT);
    fused_kernel<<<dim3(256), 512, 0, stream>>>(x, z, UT, WcT, bias, out);
}